// Round 1
// baseline (403.111 us; speedup 1.0000x reference)
//
#include <hip/hip_runtime.h>

// Problem constants (from reference): V=100000, H=128, B=1024, L=512
#define GAT_H 128
#define GAT_L 512
#define GAT_B 1024

__global__ __launch_bounds__(256) void gat_kernel(
    const float* __restrict__ emb,
    const float* __restrict__ a,
    const int* __restrict__ seq,
    const int* __restrict__ seq_l,
    float* __restrict__ out)
{
    // One 64-lane wave per (b,l) position; lane i holds elements {2i, 2i+1}.
    const int wave_id = (blockIdx.x * blockDim.x + threadIdx.x) >> 6;
    const int lane = threadIdx.x & 63;
    if (wave_id >= GAT_B * GAT_L) return;
    const int b = wave_id >> 9;    // / L
    const int l = wave_id & 511;   // % L

    const int sl  = seq_l[b];
    const int tok = seq[b * GAT_L + l];
    const float2* row = (const float2*)(emb + (size_t)tok * GAT_H);
    const float2  e   = row[lane];
    float2* orow = (float2*)(out + (size_t)wave_id * GAT_H);

    // valid = l < seq_l[b]-1 ; wave-uniform branch (whole wave shares (b,l))
    const bool valid = (l < sl - 1);
    if (!valid) {
        orow[lane] = e;   // out = raw embedding at invalid tail positions
        return;
    }

    const float pos = (float)(sl - l);
    const float2 x = make_float2(e.x + pos, e.y + pos);

    float2 xn;
    if (l + 1 < GAT_L) {
        const int tok_n = seq[b * GAT_L + l + 1];
        const float2* rown = (const float2*)(emb + (size_t)tok_n * GAT_H);
        const float2 en = rown[lane];
        const float posn = (float)(sl - (l + 1));
        xn = make_float2(en.x + posn, en.y + posn);
    } else {
        xn = make_float2(0.0f, 0.0f);
    }

    // a has shape (2H, 1): a1 = a[0:H], a2 = a[H:2H]
    const float2 a1 = ((const float2*)a)[lane];
    const float2 a2 = ((const float2*)(a + GAT_H))[lane];

    float d1 = x.x  * a1.x + x.y  * a1.y;   // dot(x,  a1) partial
    float d2 = x.x  * a2.x + x.y  * a2.y;   // dot(x,  a2) partial
    float d3 = xn.x * a2.x + xn.y * a2.y;   // dot(xn, a2) partial

    // wave-wide sum (64 lanes)
    #pragma unroll
    for (int m = 32; m >= 1; m >>= 1) {
        d1 += __shfl_xor(d1, m, 64);
        d2 += __shfl_xor(d2, m, 64);
        d3 += __shfl_xor(d3, m, 64);
    }

    const float s0 = d1 + d2;
    const float s1 = d1 + d3;
    const float mx = fmaxf(s0, s1);
    const float p0 = __expf(s0 - mx);
    const float p1 = __expf(s1 - mx);
    const float inv = 1.0f / (p0 + p1);
    const float att0 = p0 * inv;
    const float att1 = p1 * inv;

    orow[lane] = make_float2(att0 * x.x + att1 * xn.x,
                             att0 * x.y + att1 * xn.y);
}

extern "C" void kernel_launch(void* const* d_in, const int* in_sizes, int n_in,
                              void* d_out, int out_size, void* d_ws, size_t ws_size,
                              hipStream_t stream) {
    const float* emb   = (const float*)d_in[0];
    const float* a     = (const float*)d_in[1];
    const int*   seq   = (const int*)d_in[2];
    const int*   seq_l = (const int*)d_in[3];
    float* out = (float*)d_out;

    // B*L = 524288 waves, 4 waves (256 threads) per block
    const int n_waves = GAT_B * GAT_L;
    const int blocks = n_waves / 4;
    gat_kernel<<<blocks, 256, 0, stream>>>(emb, a, seq, seq_l, out);
}

// Round 2
// 354.480 us; speedup vs baseline: 1.1372x; 1.1372x over previous
//
#include <hip/hip_runtime.h>

// Problem constants: V=100000, H=128, B=1024, L=512
#define V_TOK 100000
#define GAT_H 128
#define GAT_L 512
#define GAT_B 1024
#define CHUNK 8   // consecutive positions per wave; loads CHUNK+1 rows instead of 2*CHUNK

// ---- kernel 0: S1 = sum(a1), S2 = sum(a2) -> sbuf[0..1] (one wave) ----
__global__ void k_sums(const float* __restrict__ a, float* __restrict__ sbuf) {
    const int lane = threadIdx.x & 63;
    const float2 a1 = ((const float2*)a)[lane];
    const float2 a2 = ((const float2*)(a + GAT_H))[lane];
    float s1 = a1.x + a1.y, s2 = a2.x + a2.y;
    #pragma unroll
    for (int m = 32; m >= 1; m >>= 1) {
        s1 += __shfl_xor(s1, m, 64);
        s2 += __shfl_xor(s2, m, 64);
    }
    if (lane == 0) { sbuf[0] = s1; sbuf[1] = s2; }
}

// ---- kernel 1: per-token dots t1[v]=emb[v].a1, t2[v]=emb[v].a2 ----
__global__ __launch_bounds__(256) void k_tok(const float* __restrict__ emb,
                                             const float* __restrict__ a,
                                             float* __restrict__ t1,
                                             float* __restrict__ t2) {
    const int wid = (blockIdx.x * blockDim.x + threadIdx.x) >> 6;
    const int lane = threadIdx.x & 63;
    if (wid >= V_TOK) return;
    const float2 e  = ((const float2*)(emb + (size_t)wid * GAT_H))[lane];
    const float2 a1 = ((const float2*)a)[lane];
    const float2 a2 = ((const float2*)(a + GAT_H))[lane];
    float d1 = e.x * a1.x + e.y * a1.y;
    float d2 = e.x * a2.x + e.y * a2.y;
    #pragma unroll
    for (int m = 32; m >= 1; m >>= 1) {
        d1 += __shfl_xor(d1, m, 64);
        d2 += __shfl_xor(d2, m, 64);
    }
    if (lane == 0) { t1[wid] = d1; t2[wid] = d2; }
}

// ---- kernel 2: main. One wave per CHUNK consecutive positions of one b. ----
// Scores come from token-dot tables (no reductions); each emb row loaded once
// per chunk (streamed, reused as both x_l and x_{l+1}).
__global__ __launch_bounds__(256) void k_main(const float* __restrict__ emb,
                                              const int* __restrict__ seq,
                                              const int* __restrict__ seq_l,
                                              const float* __restrict__ t1,
                                              const float* __restrict__ t2,
                                              const float* __restrict__ sbuf,
                                              float* __restrict__ out) {
    const int wid  = (blockIdx.x * blockDim.x + threadIdx.x) >> 6;
    const int lane = threadIdx.x & 63;
    const int n_chunks = GAT_L / CHUNK;
    const int b  = wid / n_chunks;
    const int l0 = (wid - b * n_chunks) * CHUNK;
    if (b >= GAT_B) return;

    const int sl = __builtin_amdgcn_readfirstlane(seq_l[b]);
    const float S1 = sbuf[0], S2 = sbuf[1];

    int tok = __builtin_amdgcn_readfirstlane(seq[b * GAT_L + l0]);
    float2 R = ((const float2*)(emb + (size_t)tok * GAT_H))[lane];
    float t1c = t1[tok], t2c = t2[tok];
    float2* obase = (float2*)(out + ((size_t)b * GAT_L + l0) * GAT_H);

    #pragma unroll
    for (int k = 0; k < CHUNK; ++k) {
        const int l = l0 + k;
        const bool valid = (l < sl - 1);            // wave-uniform
        const bool need_next = valid || (k < CHUNK - 1);
        float2 Rn; float t1n = 0.f, t2n = 0.f;
        if (need_next) {
            // valid => l+1 <= sl-1 <= 510 < L; k<CHUNK-1 => l+1 within chunk
            const int tokn = __builtin_amdgcn_readfirstlane(seq[b * GAT_L + l + 1]);
            Rn  = ((const float2*)(emb + (size_t)tokn * GAT_H))[lane];
            t1n = t1[tokn]; t2n = t2[tokn];
        }
        if (valid) {
            const float pos  = (float)(sl - l);
            const float posn = pos - 1.0f;
            const float d1  = t1c + pos * S1;
            const float d2  = t2c + pos * S2;
            const float d2n = t2n + posn * S2;     // = next position's self-a2 dot
            const float s0 = d1 + d2, s1 = d1 + d2n;
            const float mx = fmaxf(s0, s1);
            const float p0 = __expf(s0 - mx), p1 = __expf(s1 - mx);
            const float inv = 1.0f / (p0 + p1);
            const float att0 = p0 * inv, att1 = p1 * inv;
            float2 o;
            o.x = att0 * (R.x + pos) + att1 * (Rn.x + posn);
            o.y = att0 * (R.y + pos) + att1 * (Rn.y + posn);
            obase[(size_t)k * 64 + lane] = o;
        } else {
            obase[(size_t)k * 64 + lane] = R;       // out = raw embedding
        }
        if (need_next) { R = Rn; t1c = t1n; t2c = t2n; }
    }
}

extern "C" void kernel_launch(void* const* d_in, const int* in_sizes, int n_in,
                              void* d_out, int out_size, void* d_ws, size_t ws_size,
                              hipStream_t stream) {
    const float* emb   = (const float*)d_in[0];
    const float* a     = (const float*)d_in[1];
    const int*   seq   = (const int*)d_in[2];
    const int*   seq_l = (const int*)d_in[3];
    float* out = (float*)d_out;

    float* t1   = (float*)d_ws;             // V floats
    float* t2   = t1 + V_TOK;               // V floats
    float* sbuf = t2 + V_TOK;               // 2 floats

    k_sums<<<1, 64, 0, stream>>>(a, sbuf);

    {   // per-token dots: one wave per token
        const int waves = V_TOK;
        const int blocks = (waves * 64 + 255) / 256;
        k_tok<<<blocks, 256, 0, stream>>>(emb, a, t1, t2);
    }

    {   // main: B * (L/CHUNK) waves
        const int waves = GAT_B * (GAT_L / CHUNK);
        const int blocks = (waves * 64 + 255) / 256;
        k_main<<<blocks, 256, 0, stream>>>(emb, seq, seq_l, t1, t2, sbuf, out);
    }
}